// Round 6
// baseline (331.084 us; speedup 1.0000x reference)
//
#include <hip/hip_runtime.h>

constexpr int Bn  = 2;
constexpr int Sn  = 2048;
constexpr int Dn  = 1024;
constexpr int Hn  = 16;
constexpr int HDn = 64;
constexpr int Mn  = Bn * Sn;   // 4096

typedef _Float16 half8 __attribute__((ext_vector_type(8)));
typedef _Float16 half4 __attribute__((ext_vector_type(4)));
typedef float    f32x4 __attribute__((ext_vector_type(4)));

// async global->LDS, 16B per lane. LDS dest must be wave-uniform base + lane*16.
__device__ __forceinline__ void cp16(const _Float16* g, _Float16* l) {
  __builtin_amdgcn_global_load_lds(
      (__attribute__((address_space(1))) void*)g,
      (__attribute__((address_space(3))) void*)l, 16, 0, 0);
}

// ---------------------------------------------------------------------------
// prep 1: fp32 -> f16 convert of the three activation inputs.
// ---------------------------------------------------------------------------
__global__ __launch_bounds__(256) void convert_x(
    const float* __restrict__ q, const float* __restrict__ k,
    const float* __restrict__ v, _Float16* __restrict__ Xh) {
  const int z = blockIdx.y;
  const float* src = (z == 0) ? q : (z == 1) ? k : v;
  _Float16* dst = Xh + (size_t)z * (Mn * Dn);
  int i = blockIdx.x * 256 + threadIdx.x;       // float4 slot
  float4 v4 = ((const float4*)src)[i];
  half4 h;
  h.x = (_Float16)v4.x; h.y = (_Float16)v4.y;
  h.z = (_Float16)v4.z; h.w = (_Float16)v4.w;
  *(half4*)(dst + (size_t)i * 4) = h;
}

// ---------------------------------------------------------------------------
// prep 2: W[k][n] fp32 -> WT[n][k] f16 (all four weight matrices).
// ---------------------------------------------------------------------------
__global__ __launch_bounds__(256) void transpose_w(
    const float* __restrict__ Wq, const float* __restrict__ Wk,
    const float* __restrict__ Wv, const float* __restrict__ Wo,
    _Float16* __restrict__ WT) {
  const int z = blockIdx.z;
  const float* W = (z == 0) ? Wq : (z == 1) ? Wk : (z == 2) ? Wv : Wo;
  _Float16* T = WT + (size_t)z * Dn * Dn;
  __shared__ float tile[64][65];
  const int k0 = blockIdx.y * 64, n0 = blockIdx.x * 64;
  const int tid = threadIdx.x;
#pragma unroll
  for (int i = 0; i < 4; i++) {
    int s = tid + i * 256;
    int r = s >> 4, c4 = s & 15;
    float4 w4 = *(const float4*)(W + (size_t)(k0 + r) * Dn + n0 + c4 * 4);
    tile[r][c4 * 4 + 0] = w4.x; tile[r][c4 * 4 + 1] = w4.y;
    tile[r][c4 * 4 + 2] = w4.z; tile[r][c4 * 4 + 3] = w4.w;
  }
  __syncthreads();
#pragma unroll
  for (int i = 0; i < 2; i++) {
    int s = tid + i * 256;
    int n = s >> 3, r8 = (s & 7) * 8;
    half8 h;
#pragma unroll
    for (int j = 0; j < 8; j++) h[j] = (_Float16)tile[r8 + j][n];
    *(half8*)(T + (size_t)(n0 + n) * Dn + k0 + r8) = h;
  }
}

// ---------------------------------------------------------------------------
// Kernel 1: QKV projection (m97 structure, BK=32). z<2: transposed MFMA ->
// packed half4 stores; z=2 -> V pre-transposed [b][h][hd][s].
// Q pre-scaled by 0.125*log2(e) (exp2-domain fixed-shift softmax).
// ---------------------------------------------------------------------------
__global__ __launch_bounds__(256) void proj_kernel(
    const _Float16* __restrict__ Xh, const _Float16* __restrict__ WT,
    const float* __restrict__ bq, const float* __restrict__ bk,
    const float* __restrict__ bv,
    _Float16* __restrict__ Qh, _Float16* __restrict__ Kh,
    _Float16* __restrict__ VT) {
  const int z = blockIdx.z;
  const _Float16* A  = Xh + (size_t)z * Mn * Dn;
  const _Float16* Bm = WT + (size_t)z * Dn * Dn;
  const float* bias = (z == 0) ? bq : (z == 1) ? bk : bv;

  __shared__ __align__(16) _Float16 As[128 * 32];   // [m][k]
  __shared__ __align__(16) _Float16 Bs[128 * 32];   // [n][k]

  const int tid  = threadIdx.x;
  const int lane = tid & 63;
  const int w    = tid >> 6;
  const int wm   = (w >> 1) * 64;
  const int wn   = (w & 1) * 64;
  const int m0   = blockIdx.y * 128;
  const int n0   = blockIdx.x * 128;
  const int qd   = lane >> 4;
  const int lm   = lane & 15;

  f32x4 acc[4][4];
#pragma unroll
  for (int i = 0; i < 4; i++)
#pragma unroll
    for (int j = 0; j < 4; j++) acc[i][j] = {0.f, 0.f, 0.f, 0.f};

  for (int k0 = 0; k0 < Dn; k0 += 32) {
#pragma unroll
    for (int p = 0; p < 2; p++) {
      int s = tid + p * 256;              // 0..511, 16B slots
      int row = s >> 2, c = s & 3;
      cp16(A + (size_t)(m0 + row) * Dn + k0 + c * 8, As + s * 8);
    }
#pragma unroll
    for (int p = 0; p < 2; p++) {
      int s = tid + p * 256;
      int row = s >> 2, c = s & 3;
      cp16(Bm + (size_t)(n0 + row) * Dn + k0 + c * 8, Bs + s * 8);
    }
    __syncthreads();
    half8 a[4], bb[4];
#pragma unroll
    for (int mi = 0; mi < 4; mi++)
      a[mi] = *(const half8*)(As + (wm + mi * 16 + lm) * 32 + qd * 8);
#pragma unroll
    for (int ni = 0; ni < 4; ni++)
      bb[ni] = *(const half8*)(Bs + (wn + ni * 16 + lm) * 32 + qd * 8);
    if (z < 2) {
      // transposed: D rows = n (features), cols = m (tokens)
#pragma unroll
      for (int mi = 0; mi < 4; mi++)
#pragma unroll
        for (int ni = 0; ni < 4; ni++)
          acc[mi][ni] = __builtin_amdgcn_mfma_f32_16x16x32_f16(bb[ni], a[mi], acc[mi][ni], 0, 0, 0);
    } else {
#pragma unroll
      for (int mi = 0; mi < 4; mi++)
#pragma unroll
        for (int ni = 0; ni < 4; ni++)
          acc[mi][ni] = __builtin_amdgcn_mfma_f32_16x16x32_f16(a[mi], bb[ni], acc[mi][ni], 0, 0, 0);
    }
    __syncthreads();
  }

  if (z < 2) {
    _Float16* out = (z == 0) ? Qh : Kh;
    const float scl = (z == 0) ? 0.125f * 1.44269504089f : 1.0f;
#pragma unroll
    for (int mi = 0; mi < 4; mi++) {
      int m = m0 + wm + mi * 16 + lm;            // token (D col)
      int b_ = m >> 11, s_ = m & (Sn - 1);
#pragma unroll
      for (int ni = 0; ni < 4; ni++) {
        int nb = n0 + wn + ni * 16 + qd * 4;     // feature base (D rows)
        float4 b4 = *(const float4*)(bias + nb);
        int h = nb >> 6, hd = nb & 63;
        half4 h4;
        h4[0] = (_Float16)((acc[mi][ni][0] + b4.x) * scl);
        h4[1] = (_Float16)((acc[mi][ni][1] + b4.y) * scl);
        h4[2] = (_Float16)((acc[mi][ni][2] + b4.z) * scl);
        h4[3] = (_Float16)((acc[mi][ni][3] + b4.w) * scl);
        *(half4*)(out + (((size_t)(b_ * Hn + h)) * Sn + s_) * HDn + hd) = h4;
      }
    }
  } else {
#pragma unroll
    for (int ni = 0; ni < 4; ni++) {
      int n = n0 + wn + ni * 16 + lm;
      float b_f = bias[n];
      int h = n >> 6, hd = n & 63;
#pragma unroll
      for (int mi = 0; mi < 4; mi++) {
        int mb = m0 + wm + mi * 16 + qd * 4;
        int b_ = mb >> 11, s_ = mb & (Sn - 1);
        half4 h4;
#pragma unroll
        for (int r = 0; r < 4; r++) h4[r] = (_Float16)(acc[mi][ni][r] + b_f);
        *(half4*)(VT + (((size_t)(b_ * Hn + h)) * HDn + hd) * Sn + s_) = h4;
      }
    }
  }
}

// ---------------------------------------------------------------------------
// Kernel 2: flash attention, barrier-free. K/V/Q MFMA fragments are loaded
// DIRECTLY from global (L2-resident: each bh's K/V reused by 16 q-blocks;
// 64B-segment coalescing: 4 qd-lanes x 16B contiguous per row). LDS holds
// ONLY the wave-private P round-trip (C-layout -> A-operand transform).
// Fixed-shift softmax: p = exp2(qk*0.125*log2e - 10), shift in acc init.
// Row-sum l on the MFMA pipe via ones-fragment. O computed transposed.
// ---------------------------------------------------------------------------
__global__ __launch_bounds__(256) void attn_kernel(
    const _Float16* __restrict__ Qh, const _Float16* __restrict__ Kh,
    const _Float16* __restrict__ VT, _Float16* __restrict__ attn_out) {
  constexpr int PV_LD = 136;   // 128 + 8 pad
  __shared__ __align__(16) _Float16 Ps[4 * 32 * PV_LD];   // per-wave P tiles

  const int bh = blockIdx.y;
  const int q0 = blockIdx.x * 128;
  const size_t base = (size_t)bh * Sn * HDn;   // same stride for Qh/Kh/VT

  const int tid  = threadIdx.x;
  const int lane = tid & 63;
  const int w    = tid >> 6;
  const int qd   = lane >> 4;
  const int lm   = lane & 15;

  // Q fragments direct from global (B-operand of S^T = K Q^T)
  const _Float16* qptr = Qh + base + (size_t)(q0 + w * 32 + lm) * HDn + qd * 8;
  half8 qa[2][2];
#pragma unroll
  for (int nj = 0; nj < 2; nj++)
#pragma unroll
    for (int ks = 0; ks < 2; ks++)
      qa[nj][ks] = *(const half8*)(qptr + nj * 16 * HDn + ks * 32);

  // ones A-fragment for the l row-sum MFMA: A[0][k]=1, other rows 0
  half8 vones;
#pragma unroll
  for (int j = 0; j < 8; j++) vones[j] = (lm == 0) ? (_Float16)1.0f : (_Float16)0.0f;

  f32x4 oacc[2][4];      // O^T: rows=hd, cols=q
#pragma unroll
  for (int i = 0; i < 2; i++)
#pragma unroll
    for (int j = 0; j < 4; j++) oacc[i][j] = {0.f, 0.f, 0.f, 0.f};
  f32x4 oaccl[2] = {{0.f, 0.f, 0.f, 0.f}, {0.f, 0.f, 0.f, 0.f}};  // l in row 0

  _Float16* Psw = Ps + w * (32 * PV_LD);
  const f32x4 sinit = {-10.f, -10.f, -10.f, -10.f};   // fixed softmax shift

  const _Float16* kptr = Kh + base + (size_t)lm * HDn + qd * 8;
  const _Float16* vptr = VT + base + (size_t)lm * Sn + qd * 8;

  for (int kt = 0; kt < Sn / 128; kt++) {
    const int kb = kt * 128;

    // K fragments direct from global (16 b128 in flight)
    half8 ka[8][2];
#pragma unroll
    for (int ni = 0; ni < 8; ni++)
#pragma unroll
      for (int ks = 0; ks < 2; ks++)
        ka[ni][ks] = *(const half8*)(kptr + (size_t)(kb + ni * 16) * HDn + ks * 32);

    // S^T = K Q^T, accumulator pre-loaded with -shift
    f32x4 sacc[8][2];
#pragma unroll
    for (int ni = 0; ni < 8; ni++)
#pragma unroll
      for (int nj = 0; nj < 2; nj++) sacc[ni][nj] = sinit;
#pragma unroll
    for (int ni = 0; ni < 8; ni++)
#pragma unroll
      for (int ks = 0; ks < 2; ks++)
#pragma unroll
        for (int nj = 0; nj < 2; nj++)
          sacc[ni][nj] = __builtin_amdgcn_mfma_f32_16x16x32_f16(ka[ni][ks], qa[nj][ks], sacc[ni][nj], 0, 0, 0);

    // p = exp2(s), pack, store to wave-private LDS (no barriers anywhere)
#pragma unroll
    for (int nj = 0; nj < 2; nj++)
#pragma unroll
      for (int ni = 0; ni < 8; ni++) {
        float p0 = __builtin_amdgcn_exp2f(sacc[ni][nj][0]);
        float p1 = __builtin_amdgcn_exp2f(sacc[ni][nj][1]);
        float p2 = __builtin_amdgcn_exp2f(sacc[ni][nj][2]);
        float p3 = __builtin_amdgcn_exp2f(sacc[ni][nj][3]);
        auto lo = __builtin_amdgcn_cvt_pkrtz(p0, p1);   // __fp16 ext_vector(2)
        auto hi = __builtin_amdgcn_cvt_pkrtz(p2, p3);
        half4 h4;
        h4[0] = (_Float16)lo[0]; h4[1] = (_Float16)lo[1];
        h4[2] = (_Float16)hi[0]; h4[3] = (_Float16)hi[1];
        *(half4*)(Psw + (nj * 16 + lm) * PV_LD + ni * 16 + qd * 4) = h4;
      }

    // O^T += V^T P^T ; l += ones . P   (V^T fragments direct from global)
#pragma unroll
    for (int ks = 0; ks < 4; ks++) {
      half8 pa[2];
#pragma unroll
      for (int mi = 0; mi < 2; mi++)
        pa[mi] = *(const half8*)(Psw + (mi * 16 + lm) * PV_LD + ks * 32 + qd * 8);
#pragma unroll
      for (int oi = 0; oi < 4; oi++) {
        half8 vb = *(const half8*)(vptr + (size_t)(oi * 16) * Sn + kb + ks * 32);
#pragma unroll
        for (int mi = 0; mi < 2; mi++)
          oacc[mi][oi] = __builtin_amdgcn_mfma_f32_16x16x32_f16(vb, pa[mi], oacc[mi][oi], 0, 0, 0);
      }
#pragma unroll
      for (int mi = 0; mi < 2; mi++)
        oaccl[mi] = __builtin_amdgcn_mfma_f32_16x16x32_f16(vones, pa[mi], oaccl[mi], 0, 0, 0);
    }
  }

  // finalize: O^T cols = q (lm), l[q] lives in lane (qd=0, lm=q) reg 0.
  const int b_ = bh >> 4, h_ = bh & 15;
#pragma unroll
  for (int mi = 0; mi < 2; mi++) {
    float lr = __shfl(oaccl[mi][0], lm, 64);   // bpermute from qd=0 lanes
    float inv = 1.0f / lr;
    int qrow = q0 + w * 32 + mi * 16 + lm;
    size_t rowbase = ((size_t)(b_ * Sn + qrow)) * Dn + h_ * 64;
#pragma unroll
    for (int oi = 0; oi < 4; oi++) {
      half4 h4;
#pragma unroll
      for (int r = 0; r < 4; r++) h4[r] = (_Float16)(oacc[mi][oi][r] * inv);
      *(half4*)(attn_out + rowbase + oi * 16 + qd * 4) = h4;
    }
  }
}

// ---------------------------------------------------------------------------
// Kernel 3: output projection, transposed MFMA -> float4 stores.
// ---------------------------------------------------------------------------
__global__ __launch_bounds__(256) void outproj_kernel(
    const _Float16* __restrict__ Aattn, const _Float16* __restrict__ WoT,
    const float* __restrict__ bo, float* __restrict__ out) {
  __shared__ __align__(16) _Float16 As[128 * 32];
  __shared__ __align__(16) _Float16 Bs[128 * 32];

  const int tid  = threadIdx.x;
  const int lane = tid & 63;
  const int w    = tid >> 6;
  const int wm   = (w >> 1) * 64;
  const int wn   = (w & 1) * 64;
  const int m0   = blockIdx.y * 128;
  const int n0   = blockIdx.x * 128;
  const int qd   = lane >> 4;
  const int lm   = lane & 15;

  f32x4 acc[4][4];
#pragma unroll
  for (int i = 0; i < 4; i++)
#pragma unroll
    for (int j = 0; j < 4; j++) acc[i][j] = {0.f, 0.f, 0.f, 0.f};

  for (int k0 = 0; k0 < Dn; k0 += 32) {
#pragma unroll
    for (int p = 0; p < 2; p++) {
      int s = tid + p * 256;
      int row = s >> 2, c = s & 3;
      cp16(Aattn + (size_t)(m0 + row) * Dn + k0 + c * 8, As + s * 8);
    }
#pragma unroll
    for (int p = 0; p < 2; p++) {
      int s = tid + p * 256;
      int row = s >> 2, c = s & 3;
      cp16(WoT + (size_t)(n0 + row) * Dn + k0 + c * 8, Bs + s * 8);
    }
    __syncthreads();
    half8 a[4], bb[4];
#pragma unroll
    for (int mi = 0; mi < 4; mi++)
      a[mi] = *(const half8*)(As + (wm + mi * 16 + lm) * 32 + qd * 8);
#pragma unroll
    for (int ni = 0; ni < 4; ni++)
      bb[ni] = *(const half8*)(Bs + (wn + ni * 16 + lm) * 32 + qd * 8);
#pragma unroll
    for (int mi = 0; mi < 4; mi++)
#pragma unroll
      for (int ni = 0; ni < 4; ni++)
        acc[mi][ni] = __builtin_amdgcn_mfma_f32_16x16x32_f16(bb[ni], a[mi], acc[mi][ni], 0, 0, 0);
    __syncthreads();
  }
#pragma unroll
  for (int mi = 0; mi < 4; mi++) {
    int m = m0 + wm + mi * 16 + lm;              // token (D col)
#pragma unroll
    for (int ni = 0; ni < 4; ni++) {
      int nb = n0 + wn + ni * 16 + qd * 4;       // feature base (D rows)
      float4 b4 = *(const float4*)(bo + nb);
      float4 o4;
      o4.x = acc[mi][ni][0] + b4.x;
      o4.y = acc[mi][ni][1] + b4.y;
      o4.z = acc[mi][ni][2] + b4.z;
      o4.w = acc[mi][ni][3] + b4.w;
      *(float4*)(out + (size_t)m * Dn + nb) = o4;
    }
  }
}

extern "C" void kernel_launch(void* const* d_in, const int* in_sizes, int n_in,
                              void* d_out, int out_size, void* d_ws, size_t ws_size,
                              hipStream_t stream) {
  const float* query = (const float*)d_in[0];
  const float* key_  = (const float*)d_in[1];
  const float* value = (const float*)d_in[2];
  const float* Wq = (const float*)d_in[3];
  const float* bq = (const float*)d_in[4];
  const float* Wk = (const float*)d_in[5];
  const float* bk = (const float*)d_in[6];
  const float* Wv = (const float*)d_in[7];
  const float* bv = (const float*)d_in[8];
  const float* Wo = (const float*)d_in[9];
  const float* bo = (const float*)d_in[10];

  _Float16* Xh = (_Float16*)d_ws;                  // [3][4096][1024] f16 = 25.2 MB
  _Float16* WT = Xh + (size_t)3 * Mn * Dn;         // [4][1024][1024] f16 = 8.4 MB
  _Float16* Qh = WT + (size_t)4 * Dn * Dn;         // [b][h][s][hd]  8.4 MB
  _Float16* Kh = Qh + (size_t)Mn * Dn;             // [b][h][s][hd]  8.4 MB
  _Float16* VT = Kh + (size_t)Mn * Dn;             // [b][h][hd][s]  8.4 MB
  _Float16* attnb = Xh;                            // alias: Xh dead after proj
  float* out = (float*)d_out;

  dim3 blk(256);
  convert_x<<<dim3((Mn * Dn) / (4 * 256), 3), blk, 0, stream>>>(query, key_, value, Xh);
  transpose_w<<<dim3(16, 16, 4), blk, 0, stream>>>(Wq, Wk, Wv, Wo, WT);
  proj_kernel<<<dim3(Dn / 128, Mn / 128, 3), blk, 0, stream>>>(
      Xh, WT, bq, bk, bv, Qh, Kh, VT);
  attn_kernel<<<dim3(Sn / 128, Bn * Hn), blk, 0, stream>>>(Qh, Kh, VT, attnb);
  outproj_kernel<<<dim3(Dn / 128, Mn / 128), blk, 0, stream>>>(
      attnb, WT + (size_t)3 * Dn * Dn, bo, out);
}

// Round 7
// 275.805 us; speedup vs baseline: 1.2004x; 1.2004x over previous
//
#include <hip/hip_runtime.h>

constexpr int Bn  = 2;
constexpr int Sn  = 2048;
constexpr int Dn  = 1024;
constexpr int Hn  = 16;
constexpr int HDn = 64;
constexpr int Mn  = Bn * Sn;   // 4096

typedef _Float16 half8 __attribute__((ext_vector_type(8)));
typedef _Float16 half4 __attribute__((ext_vector_type(4)));
typedef float    f32x4 __attribute__((ext_vector_type(4)));

// async global->LDS, 16B per lane. LDS dest must be wave-uniform base + lane*16.
__device__ __forceinline__ void cp16(const _Float16* g, _Float16* l) {
  __builtin_amdgcn_global_load_lds(
      (__attribute__((address_space(1))) void*)g,
      (__attribute__((address_space(3))) void*)l, 16, 0, 0);
}

// ---------------------------------------------------------------------------
// prep 1: fp32 -> f16 convert of the three activation inputs.
// ---------------------------------------------------------------------------
__global__ __launch_bounds__(256) void convert_x(
    const float* __restrict__ q, const float* __restrict__ k,
    const float* __restrict__ v, _Float16* __restrict__ Xh) {
  const int z = blockIdx.y;
  const float* src = (z == 0) ? q : (z == 1) ? k : v;
  _Float16* dst = Xh + (size_t)z * (Mn * Dn);
  int i = blockIdx.x * 256 + threadIdx.x;       // float4 slot
  float4 v4 = ((const float4*)src)[i];
  half4 h;
  h.x = (_Float16)v4.x; h.y = (_Float16)v4.y;
  h.z = (_Float16)v4.z; h.w = (_Float16)v4.w;
  *(half4*)(dst + (size_t)i * 4) = h;
}

// ---------------------------------------------------------------------------
// prep 2: W[k][n] fp32 -> WT[n][k] f16 (all four weight matrices).
// ---------------------------------------------------------------------------
__global__ __launch_bounds__(256) void transpose_w(
    const float* __restrict__ Wq, const float* __restrict__ Wk,
    const float* __restrict__ Wv, const float* __restrict__ Wo,
    _Float16* __restrict__ WT) {
  const int z = blockIdx.z;
  const float* W = (z == 0) ? Wq : (z == 1) ? Wk : (z == 2) ? Wv : Wo;
  _Float16* T = WT + (size_t)z * Dn * Dn;
  __shared__ float tile[64][65];
  const int k0 = blockIdx.y * 64, n0 = blockIdx.x * 64;
  const int tid = threadIdx.x;
#pragma unroll
  for (int i = 0; i < 4; i++) {
    int s = tid + i * 256;
    int r = s >> 4, c4 = s & 15;
    float4 w4 = *(const float4*)(W + (size_t)(k0 + r) * Dn + n0 + c4 * 4);
    tile[r][c4 * 4 + 0] = w4.x; tile[r][c4 * 4 + 1] = w4.y;
    tile[r][c4 * 4 + 2] = w4.z; tile[r][c4 * 4 + 3] = w4.w;
  }
  __syncthreads();
#pragma unroll
  for (int i = 0; i < 2; i++) {
    int s = tid + i * 256;
    int n = s >> 3, r8 = (s & 7) * 8;
    half8 h;
#pragma unroll
    for (int j = 0; j < 8; j++) h[j] = (_Float16)tile[r8 + j][n];
    *(half8*)(T + (size_t)(n0 + n) * Dn + k0 + r8) = h;
  }
}

// ---------------------------------------------------------------------------
// Kernel 1: QKV projection (m97 structure, BK=32). z<2: transposed MFMA ->
// packed half4 stores; z=2 -> V pre-transposed [b][h][hd][s].
// Q pre-scaled by 0.125*log2(e) (exp2-domain fixed-shift softmax).
// ---------------------------------------------------------------------------
__global__ __launch_bounds__(256) void proj_kernel(
    const _Float16* __restrict__ Xh, const _Float16* __restrict__ WT,
    const float* __restrict__ bq, const float* __restrict__ bk,
    const float* __restrict__ bv,
    _Float16* __restrict__ Qh, _Float16* __restrict__ Kh,
    _Float16* __restrict__ VT) {
  const int z = blockIdx.z;
  const _Float16* A  = Xh + (size_t)z * Mn * Dn;
  const _Float16* Bm = WT + (size_t)z * Dn * Dn;
  const float* bias = (z == 0) ? bq : (z == 1) ? bk : bv;

  __shared__ __align__(16) _Float16 As[128 * 32];   // [m][k]
  __shared__ __align__(16) _Float16 Bs[128 * 32];   // [n][k]

  const int tid  = threadIdx.x;
  const int lane = tid & 63;
  const int w    = tid >> 6;
  const int wm   = (w >> 1) * 64;
  const int wn   = (w & 1) * 64;
  const int m0   = blockIdx.y * 128;
  const int n0   = blockIdx.x * 128;
  const int qd   = lane >> 4;
  const int lm   = lane & 15;

  f32x4 acc[4][4];
#pragma unroll
  for (int i = 0; i < 4; i++)
#pragma unroll
    for (int j = 0; j < 4; j++) acc[i][j] = {0.f, 0.f, 0.f, 0.f};

  for (int k0 = 0; k0 < Dn; k0 += 32) {
#pragma unroll
    for (int p = 0; p < 2; p++) {
      int s = tid + p * 256;              // 0..511, 16B slots
      int row = s >> 2, c = s & 3;
      cp16(A + (size_t)(m0 + row) * Dn + k0 + c * 8, As + s * 8);
    }
#pragma unroll
    for (int p = 0; p < 2; p++) {
      int s = tid + p * 256;
      int row = s >> 2, c = s & 3;
      cp16(Bm + (size_t)(n0 + row) * Dn + k0 + c * 8, Bs + s * 8);
    }
    __syncthreads();
    half8 a[4], bb[4];
#pragma unroll
    for (int mi = 0; mi < 4; mi++)
      a[mi] = *(const half8*)(As + (wm + mi * 16 + lm) * 32 + qd * 8);
#pragma unroll
    for (int ni = 0; ni < 4; ni++)
      bb[ni] = *(const half8*)(Bs + (wn + ni * 16 + lm) * 32 + qd * 8);
    if (z < 2) {
      // transposed: D rows = n (features), cols = m (tokens)
#pragma unroll
      for (int mi = 0; mi < 4; mi++)
#pragma unroll
        for (int ni = 0; ni < 4; ni++)
          acc[mi][ni] = __builtin_amdgcn_mfma_f32_16x16x32_f16(bb[ni], a[mi], acc[mi][ni], 0, 0, 0);
    } else {
#pragma unroll
      for (int mi = 0; mi < 4; mi++)
#pragma unroll
        for (int ni = 0; ni < 4; ni++)
          acc[mi][ni] = __builtin_amdgcn_mfma_f32_16x16x32_f16(a[mi], bb[ni], acc[mi][ni], 0, 0, 0);
    }
    __syncthreads();
  }

  if (z < 2) {
    _Float16* out = (z == 0) ? Qh : Kh;
    const float scl = (z == 0) ? 0.125f * 1.44269504089f : 1.0f;
#pragma unroll
    for (int mi = 0; mi < 4; mi++) {
      int m = m0 + wm + mi * 16 + lm;            // token (D col)
      int b_ = m >> 11, s_ = m & (Sn - 1);
#pragma unroll
      for (int ni = 0; ni < 4; ni++) {
        int nb = n0 + wn + ni * 16 + qd * 4;     // feature base (D rows)
        float4 b4 = *(const float4*)(bias + nb);
        int h = nb >> 6, hd = nb & 63;
        half4 h4;
        h4[0] = (_Float16)((acc[mi][ni][0] + b4.x) * scl);
        h4[1] = (_Float16)((acc[mi][ni][1] + b4.y) * scl);
        h4[2] = (_Float16)((acc[mi][ni][2] + b4.z) * scl);
        h4[3] = (_Float16)((acc[mi][ni][3] + b4.w) * scl);
        *(half4*)(out + (((size_t)(b_ * Hn + h)) * Sn + s_) * HDn + hd) = h4;
      }
    }
  } else {
#pragma unroll
    for (int ni = 0; ni < 4; ni++) {
      int n = n0 + wn + ni * 16 + lm;
      float b_f = bias[n];
      int h = n >> 6, hd = n & 63;
#pragma unroll
      for (int mi = 0; mi < 4; mi++) {
        int mb = m0 + wm + mi * 16 + qd * 4;
        int b_ = mb >> 11, s_ = mb & (Sn - 1);
        half4 h4;
#pragma unroll
        for (int r = 0; r < 4; r++) h4[r] = (_Float16)(acc[mi][ni][r] + b_f);
        *(half4*)(VT + (((size_t)(b_ * Hn + h)) * HDn + hd) * Sn + s_) = h4;
      }
    }
  }
}

// ---------------------------------------------------------------------------
// Kernel 2: flash attention, restructured K-loop (1 barrier/kt):
//  - K tile staged via global_load_lds into a DOUBLE BUFFER, prefetched one
//    full kt ahead (DMA: no staging VGPRs/ds_writes). XOR swizzle (granule
//    u' = u ^ (row&7)) applied on the GLOBAL source side -> conflict-free
//    reads without padding (cp16 cannot pad).
//  - V fragments loaded direct global -> registers, issued after the S^T
//    MFMAs, consumed ~300 cyc later in PV (latency decoupled).
//  - Q fragments direct global, once per block.
//  - Fixed-shift softmax p = exp2(s - 10) (shift in acc init, scale folded
//    into Q projection); row-sum l on the MFMA pipe via ones-fragment.
//  - O computed transposed -> packed half4 stores. LDS: 2x16K (K) + 34.8K (P).
// ---------------------------------------------------------------------------
__global__ __launch_bounds__(256) void attn_kernel(
    const _Float16* __restrict__ Qh, const _Float16* __restrict__ Kh,
    const _Float16* __restrict__ VT, _Float16* __restrict__ attn_out) {
  constexpr int PV_LD = 136;   // 128 + 8 pad
  __shared__ __align__(16) _Float16 Ksb[2][128 * 64];     // swizzled K tiles
  __shared__ __align__(16) _Float16 Ps[4 * 32 * PV_LD];   // per-wave P tiles

  const int bh = blockIdx.y;
  const int q0 = blockIdx.x * 128;
  const size_t base = (size_t)bh * Sn * HDn;   // same stride for Qh/Kh/VT

  const int tid  = threadIdx.x;
  const int lane = tid & 63;
  const int w    = tid >> 6;
  const int qd   = lane >> 4;
  const int lm   = lane & 15;

  // Q fragments direct from global (B-operand of S^T = K Q^T), once.
  const _Float16* qptr = Qh + base + (size_t)(q0 + w * 32 + lm) * HDn + qd * 8;
  half8 qa[2][2];
#pragma unroll
  for (int nj = 0; nj < 2; nj++)
#pragma unroll
    for (int ks = 0; ks < 2; ks++)
      qa[nj][ks] = *(const half8*)(qptr + nj * 16 * HDn + ks * 32);

  // ones A-fragment for the l row-sum MFMA: A[0][k]=1, other rows 0
  half8 vones;
#pragma unroll
  for (int j = 0; j < 8; j++) vones[j] = (lm == 0) ? (_Float16)1.0f : (_Float16)0.0f;

  f32x4 oacc[2][4];      // O^T: rows=hd, cols=q
#pragma unroll
  for (int i = 0; i < 2; i++)
#pragma unroll
    for (int j = 0; j < 4; j++) oacc[i][j] = {0.f, 0.f, 0.f, 0.f};
  f32x4 oaccl[2] = {{0.f, 0.f, 0.f, 0.f}, {0.f, 0.f, 0.f, 0.f}};  // l in row 0

  _Float16* Psw = Ps + w * (32 * PV_LD);
  const f32x4 sinit = {-10.f, -10.f, -10.f, -10.f};   // fixed softmax shift

  // swizzled K stage: LDS slot s (16B) holds global granule u'^(row&7) of row s>>3
  const int st_r  = tid >> 3;              // rows 0..31 per 256-thread pass
  const int st_u  = (tid & 7) ^ (st_r & 7);
  const _Float16* kbase = Kh + base;

#define STAGE_K(KT, DST)                                                     \
  {                                                                          \
    const _Float16* src_ = kbase + (size_t)(KT) * 128 * HDn;                 \
    _Float16* dst_ = (DST);                                                  \
    _Pragma("unroll")                                                        \
    for (int p = 0; p < 4; p++)                                              \
      cp16(src_ + (size_t)(st_r + p * 32) * HDn + st_u * 8,                  \
           dst_ + (tid + p * 256) * 8);                                      \
  }

  STAGE_K(0, Ksb[0])
  __syncthreads();   // drains cp16 (vmcnt0 before barrier)

  int cur = 0;
  for (int kt = 0; kt < Sn / 128; kt++) {
    const int kb = kt * 128;
    // prefetch next K tile into the other buffer (lands by the bottom barrier)
    if (kt + 1 < Sn / 128) STAGE_K(kt + 1, Ksb[cur ^ 1])

    // S^T = K Q^T from swizzled LDS, accumulator pre-loaded with -shift
    f32x4 sacc[8][2];
#pragma unroll
    for (int ni = 0; ni < 8; ni++)
#pragma unroll
      for (int nj = 0; nj < 2; nj++) sacc[ni][nj] = sinit;
#pragma unroll
    for (int ni = 0; ni < 8; ni++)
#pragma unroll
      for (int ks = 0; ks < 2; ks++) {
        int up = (4 * ks + qd) ^ (lm & 7);   // row = ni*16+lm, row&7 == lm&7
        half8 ka = *(const half8*)(Ksb[cur] + (ni * 16 + lm) * HDn + up * 8);
#pragma unroll
        for (int nj = 0; nj < 2; nj++)
          sacc[ni][nj] = __builtin_amdgcn_mfma_f32_16x16x32_f16(ka, qa[nj][ks], sacc[ni][nj], 0, 0, 0);
      }

    // V fragments direct global -> regs (consumed in PV, ~exp-phase later)
    half8 vb[4][4];   // [oi][ks]
#pragma unroll
    for (int oi = 0; oi < 4; oi++)
#pragma unroll
      for (int ks = 0; ks < 4; ks++)
        vb[oi][ks] = *(const half8*)(VT + base + (size_t)(oi * 16 + lm) * Sn + kb + ks * 32 + qd * 8);

    // p = exp2(s), pack, store to wave-private LDS
#pragma unroll
    for (int nj = 0; nj < 2; nj++)
#pragma unroll
      for (int ni = 0; ni < 8; ni++) {
        float p0 = __builtin_amdgcn_exp2f(sacc[ni][nj][0]);
        float p1 = __builtin_amdgcn_exp2f(sacc[ni][nj][1]);
        float p2 = __builtin_amdgcn_exp2f(sacc[ni][nj][2]);
        float p3 = __builtin_amdgcn_exp2f(sacc[ni][nj][3]);
        auto lo = __builtin_amdgcn_cvt_pkrtz(p0, p1);
        auto hi = __builtin_amdgcn_cvt_pkrtz(p2, p3);
        half4 h4;
        h4[0] = (_Float16)lo[0]; h4[1] = (_Float16)lo[1];
        h4[2] = (_Float16)hi[0]; h4[3] = (_Float16)hi[1];
        *(half4*)(Psw + (nj * 16 + lm) * PV_LD + ni * 16 + qd * 4) = h4;
      }

    // O^T += V^T P^T ; l += ones . P
#pragma unroll
    for (int ks = 0; ks < 4; ks++) {
      half8 pa[2];
#pragma unroll
      for (int mi = 0; mi < 2; mi++)
        pa[mi] = *(const half8*)(Psw + (mi * 16 + lm) * PV_LD + ks * 32 + qd * 8);
#pragma unroll
      for (int oi = 0; oi < 4; oi++)
#pragma unroll
        for (int mi = 0; mi < 2; mi++)
          oacc[mi][oi] = __builtin_amdgcn_mfma_f32_16x16x32_f16(vb[oi][ks], pa[mi], oacc[mi][oi], 0, 0, 0);
#pragma unroll
      for (int mi = 0; mi < 2; mi++)
        oaccl[mi] = __builtin_amdgcn_mfma_f32_16x16x32_f16(vones, pa[mi], oaccl[mi], 0, 0, 0);
    }

    __syncthreads();   // single barrier/kt: syncs waves + drains prefetch DMA
    cur ^= 1;
  }
#undef STAGE_K

  // finalize: O^T cols = q (lm), l[q] lives in lane (qd=0, lm=q) reg 0.
  const int b_ = bh >> 4, h_ = bh & 15;
#pragma unroll
  for (int mi = 0; mi < 2; mi++) {
    float lr = __shfl(oaccl[mi][0], lm, 64);   // bpermute from qd=0 lanes
    float inv = 1.0f / lr;
    int qrow = q0 + w * 32 + mi * 16 + lm;
    size_t rowbase = ((size_t)(b_ * Sn + qrow)) * Dn + h_ * 64;
#pragma unroll
    for (int oi = 0; oi < 4; oi++) {
      half4 h4;
#pragma unroll
      for (int r = 0; r < 4; r++) h4[r] = (_Float16)(oacc[mi][oi][r] * inv);
      *(half4*)(attn_out + rowbase + oi * 16 + qd * 4) = h4;
    }
  }
}

// ---------------------------------------------------------------------------
// Kernel 3: output projection, transposed MFMA -> float4 stores.
// ---------------------------------------------------------------------------
__global__ __launch_bounds__(256) void outproj_kernel(
    const _Float16* __restrict__ Aattn, const _Float16* __restrict__ WoT,
    const float* __restrict__ bo, float* __restrict__ out) {
  __shared__ __align__(16) _Float16 As[128 * 32];
  __shared__ __align__(16) _Float16 Bs[128 * 32];

  const int tid  = threadIdx.x;
  const int lane = tid & 63;
  const int w    = tid >> 6;
  const int wm   = (w >> 1) * 64;
  const int wn   = (w & 1) * 64;
  const int m0   = blockIdx.y * 128;
  const int n0   = blockIdx.x * 128;
  const int qd   = lane >> 4;
  const int lm   = lane & 15;

  f32x4 acc[4][4];
#pragma unroll
  for (int i = 0; i < 4; i++)
#pragma unroll
    for (int j = 0; j < 4; j++) acc[i][j] = {0.f, 0.f, 0.f, 0.f};

  for (int k0 = 0; k0 < Dn; k0 += 32) {
#pragma unroll
    for (int p = 0; p < 2; p++) {
      int s = tid + p * 256;
      int row = s >> 2, c = s & 3;
      cp16(Aattn + (size_t)(m0 + row) * Dn + k0 + c * 8, As + s * 8);
    }
#pragma unroll
    for (int p = 0; p < 2; p++) {
      int s = tid + p * 256;
      int row = s >> 2, c = s & 3;
      cp16(WoT + (size_t)(n0 + row) * Dn + k0 + c * 8, Bs + s * 8);
    }
    __syncthreads();
    half8 a[4], bb[4];
#pragma unroll
    for (int mi = 0; mi < 4; mi++)
      a[mi] = *(const half8*)(As + (wm + mi * 16 + lm) * 32 + qd * 8);
#pragma unroll
    for (int ni = 0; ni < 4; ni++)
      bb[ni] = *(const half8*)(Bs + (wn + ni * 16 + lm) * 32 + qd * 8);
#pragma unroll
    for (int mi = 0; mi < 4; mi++)
#pragma unroll
      for (int ni = 0; ni < 4; ni++)
        acc[mi][ni] = __builtin_amdgcn_mfma_f32_16x16x32_f16(bb[ni], a[mi], acc[mi][ni], 0, 0, 0);
    __syncthreads();
  }
#pragma unroll
  for (int mi = 0; mi < 4; mi++) {
    int m = m0 + wm + mi * 16 + lm;              // token (D col)
#pragma unroll
    for (int ni = 0; ni < 4; ni++) {
      int nb = n0 + wn + ni * 16 + qd * 4;       // feature base (D rows)
      float4 b4 = *(const float4*)(bo + nb);
      float4 o4;
      o4.x = acc[mi][ni][0] + b4.x;
      o4.y = acc[mi][ni][1] + b4.y;
      o4.z = acc[mi][ni][2] + b4.z;
      o4.w = acc[mi][ni][3] + b4.w;
      *(float4*)(out + (size_t)m * Dn + nb) = o4;
    }
  }
}

extern "C" void kernel_launch(void* const* d_in, const int* in_sizes, int n_in,
                              void* d_out, int out_size, void* d_ws, size_t ws_size,
                              hipStream_t stream) {
  const float* query = (const float*)d_in[0];
  const float* key_  = (const float*)d_in[1];
  const float* value = (const float*)d_in[2];
  const float* Wq = (const float*)d_in[3];
  const float* bq = (const float*)d_in[4];
  const float* Wk = (const float*)d_in[5];
  const float* bk = (const float*)d_in[6];
  const float* Wv = (const float*)d_in[7];
  const float* bv = (const float*)d_in[8];
  const float* Wo = (const float*)d_in[9];
  const float* bo = (const float*)d_in[10];

  _Float16* Xh = (_Float16*)d_ws;                  // [3][4096][1024] f16 = 25.2 MB
  _Float16* WT = Xh + (size_t)3 * Mn * Dn;         // [4][1024][1024] f16 = 8.4 MB
  _Float16* Qh = WT + (size_t)4 * Dn * Dn;         // [b][h][s][hd]  8.4 MB
  _Float16* Kh = Qh + (size_t)Mn * Dn;             // [b][h][s][hd]  8.4 MB
  _Float16* VT = Kh + (size_t)Mn * Dn;             // [b][h][hd][s]  8.4 MB
  _Float16* attnb = Xh;                            // alias: Xh dead after proj
  float* out = (float*)d_out;

  dim3 blk(256);
  convert_x<<<dim3((Mn * Dn) / (4 * 256), 3), blk, 0, stream>>>(query, key_, value, Xh);
  transpose_w<<<dim3(16, 16, 4), blk, 0, stream>>>(Wq, Wk, Wv, Wo, WT);
  proj_kernel<<<dim3(Dn / 128, Mn / 128, 3), blk, 0, stream>>>(
      Xh, WT, bq, bk, bv, Qh, Kh, VT);
  attn_kernel<<<dim3(Sn / 128, Bn * Hn), blk, 0, stream>>>(Qh, Kh, VT, attnb);
  outproj_kernel<<<dim3(Dn / 128, Mn / 128), blk, 0, stream>>>(
      attnb, WT + (size_t)3 * Dn * Dn, bo, out);
}

// Round 8
// 274.599 us; speedup vs baseline: 1.2057x; 1.0044x over previous
//
#include <hip/hip_runtime.h>

constexpr int Bn  = 2;
constexpr int Sn  = 2048;
constexpr int Dn  = 1024;
constexpr int Hn  = 16;
constexpr int HDn = 64;
constexpr int Mn  = Bn * Sn;   // 4096

typedef _Float16 half8 __attribute__((ext_vector_type(8)));
typedef _Float16 half4 __attribute__((ext_vector_type(4)));
typedef float    f32x4 __attribute__((ext_vector_type(4)));

// async global->LDS, 16B per lane. LDS dest must be wave-uniform base + lane*16.
__device__ __forceinline__ void cp16(const _Float16* g, _Float16* l) {
  __builtin_amdgcn_global_load_lds(
      (__attribute__((address_space(1))) void*)g,
      (__attribute__((address_space(3))) void*)l, 16, 0, 0);
}

// ---------------------------------------------------------------------------
// prep 1: fp32 -> f16 convert of the three activation inputs.
// ---------------------------------------------------------------------------
__global__ __launch_bounds__(256) void convert_x(
    const float* __restrict__ q, const float* __restrict__ k,
    const float* __restrict__ v, _Float16* __restrict__ Xh) {
  const int z = blockIdx.y;
  const float* src = (z == 0) ? q : (z == 1) ? k : v;
  _Float16* dst = Xh + (size_t)z * (Mn * Dn);
  int i = blockIdx.x * 256 + threadIdx.x;       // float4 slot
  float4 v4 = ((const float4*)src)[i];
  half4 h;
  h.x = (_Float16)v4.x; h.y = (_Float16)v4.y;
  h.z = (_Float16)v4.z; h.w = (_Float16)v4.w;
  *(half4*)(dst + (size_t)i * 4) = h;
}

// ---------------------------------------------------------------------------
// prep 2: W[k][n] fp32 -> WT[n][k] f16 (all four weight matrices).
// ---------------------------------------------------------------------------
__global__ __launch_bounds__(256) void transpose_w(
    const float* __restrict__ Wq, const float* __restrict__ Wk,
    const float* __restrict__ Wv, const float* __restrict__ Wo,
    _Float16* __restrict__ WT) {
  const int z = blockIdx.z;
  const float* W = (z == 0) ? Wq : (z == 1) ? Wk : (z == 2) ? Wv : Wo;
  _Float16* T = WT + (size_t)z * Dn * Dn;
  __shared__ float tile[64][65];
  const int k0 = blockIdx.y * 64, n0 = blockIdx.x * 64;
  const int tid = threadIdx.x;
#pragma unroll
  for (int i = 0; i < 4; i++) {
    int s = tid + i * 256;
    int r = s >> 4, c4 = s & 15;
    float4 w4 = *(const float4*)(W + (size_t)(k0 + r) * Dn + n0 + c4 * 4);
    tile[r][c4 * 4 + 0] = w4.x; tile[r][c4 * 4 + 1] = w4.y;
    tile[r][c4 * 4 + 2] = w4.z; tile[r][c4 * 4 + 3] = w4.w;
  }
  __syncthreads();
#pragma unroll
  for (int i = 0; i < 2; i++) {
    int s = tid + i * 256;
    int n = s >> 3, r8 = (s & 7) * 8;
    half8 h;
#pragma unroll
    for (int j = 0; j < 8; j++) h[j] = (_Float16)tile[r8 + j][n];
    *(half8*)(T + (size_t)(n0 + n) * Dn + k0 + r8) = h;
  }
}

// ---------------------------------------------------------------------------
// Kernel 1: QKV projection (m97 structure, BK=32). z<2: transposed MFMA ->
// packed half4 stores; z=2 -> V pre-transposed [b][h][hd][s].
// Q pre-scaled by 0.125*log2(e) (exp2-domain fixed-shift softmax).
// ---------------------------------------------------------------------------
__global__ __launch_bounds__(256) void proj_kernel(
    const _Float16* __restrict__ Xh, const _Float16* __restrict__ WT,
    const float* __restrict__ bq, const float* __restrict__ bk,
    const float* __restrict__ bv,
    _Float16* __restrict__ Qh, _Float16* __restrict__ Kh,
    _Float16* __restrict__ VT) {
  const int z = blockIdx.z;
  const _Float16* A  = Xh + (size_t)z * Mn * Dn;
  const _Float16* Bm = WT + (size_t)z * Dn * Dn;
  const float* bias = (z == 0) ? bq : (z == 1) ? bk : bv;

  __shared__ __align__(16) _Float16 As[128 * 32];   // [m][k]
  __shared__ __align__(16) _Float16 Bs[128 * 32];   // [n][k]

  const int tid  = threadIdx.x;
  const int lane = tid & 63;
  const int w    = tid >> 6;
  const int wm   = (w >> 1) * 64;
  const int wn   = (w & 1) * 64;
  const int m0   = blockIdx.y * 128;
  const int n0   = blockIdx.x * 128;
  const int qd   = lane >> 4;
  const int lm   = lane & 15;

  f32x4 acc[4][4];
#pragma unroll
  for (int i = 0; i < 4; i++)
#pragma unroll
    for (int j = 0; j < 4; j++) acc[i][j] = {0.f, 0.f, 0.f, 0.f};

  for (int k0 = 0; k0 < Dn; k0 += 32) {
#pragma unroll
    for (int p = 0; p < 2; p++) {
      int s = tid + p * 256;              // 0..511, 16B slots
      int row = s >> 2, c = s & 3;
      cp16(A + (size_t)(m0 + row) * Dn + k0 + c * 8, As + s * 8);
    }
#pragma unroll
    for (int p = 0; p < 2; p++) {
      int s = tid + p * 256;
      int row = s >> 2, c = s & 3;
      cp16(Bm + (size_t)(n0 + row) * Dn + k0 + c * 8, Bs + s * 8);
    }
    __syncthreads();
    half8 a[4], bb[4];
#pragma unroll
    for (int mi = 0; mi < 4; mi++)
      a[mi] = *(const half8*)(As + (wm + mi * 16 + lm) * 32 + qd * 8);
#pragma unroll
    for (int ni = 0; ni < 4; ni++)
      bb[ni] = *(const half8*)(Bs + (wn + ni * 16 + lm) * 32 + qd * 8);
    if (z < 2) {
      // transposed: D rows = n (features), cols = m (tokens)
#pragma unroll
      for (int mi = 0; mi < 4; mi++)
#pragma unroll
        for (int ni = 0; ni < 4; ni++)
          acc[mi][ni] = __builtin_amdgcn_mfma_f32_16x16x32_f16(bb[ni], a[mi], acc[mi][ni], 0, 0, 0);
    } else {
#pragma unroll
      for (int mi = 0; mi < 4; mi++)
#pragma unroll
        for (int ni = 0; ni < 4; ni++)
          acc[mi][ni] = __builtin_amdgcn_mfma_f32_16x16x32_f16(a[mi], bb[ni], acc[mi][ni], 0, 0, 0);
    }
    __syncthreads();
  }

  if (z < 2) {
    _Float16* out = (z == 0) ? Qh : Kh;
    const float scl = (z == 0) ? 0.125f * 1.44269504089f : 1.0f;
#pragma unroll
    for (int mi = 0; mi < 4; mi++) {
      int m = m0 + wm + mi * 16 + lm;            // token (D col)
      int b_ = m >> 11, s_ = m & (Sn - 1);
#pragma unroll
      for (int ni = 0; ni < 4; ni++) {
        int nb = n0 + wn + ni * 16 + qd * 4;     // feature base (D rows)
        float4 b4 = *(const float4*)(bias + nb);
        int h = nb >> 6, hd = nb & 63;
        half4 h4;
        h4[0] = (_Float16)((acc[mi][ni][0] + b4.x) * scl);
        h4[1] = (_Float16)((acc[mi][ni][1] + b4.y) * scl);
        h4[2] = (_Float16)((acc[mi][ni][2] + b4.z) * scl);
        h4[3] = (_Float16)((acc[mi][ni][3] + b4.w) * scl);
        *(half4*)(out + (((size_t)(b_ * Hn + h)) * Sn + s_) * HDn + hd) = h4;
      }
    }
  } else {
#pragma unroll
    for (int ni = 0; ni < 4; ni++) {
      int n = n0 + wn + ni * 16 + lm;
      float b_f = bias[n];
      int h = n >> 6, hd = n & 63;
#pragma unroll
      for (int mi = 0; mi < 4; mi++) {
        int mb = m0 + wm + mi * 16 + qd * 4;
        int b_ = mb >> 11, s_ = mb & (Sn - 1);
        half4 h4;
#pragma unroll
        for (int r = 0; r < 4; r++) h4[r] = (_Float16)(acc[mi][ni][r] + b_f);
        *(half4*)(VT + (((size_t)(b_ * Hn + h)) * HDn + hd) * Sn + s_) = h4;
      }
    }
  }
}

// ---------------------------------------------------------------------------
// Kernel 2: flash attention. r7 pipeline (double-buffered K via
// global_load_lds w/ source-side XOR swizzle, 1 barrier/kt, direct-global V
// fragments, fixed-shift exp2 softmax, l on MFMA pipe, O^T epilogue), plus:
//  - CHUNKED P: each kt processed as two 64-key chunks -> Ps halved to
//    18.4 KB; LDS 50 KB -> 3 blocks/CU (12 waves) [was 2 blocks, 21% occ;
//    r5/r7 both pinned at 80 us = latency wall, all pipes <30%].
//  - XCD SWIZZLE: 1-D grid decoded so all 16 q-blocks of one bh land on one
//    XCD (n&7); per-XCD K/V/Q working set = 4 bh ~ 4 MB = L2 -> K/V reads
//    from local L2 (~200cyc) instead of L3 (~600+).
// ---------------------------------------------------------------------------
__global__ __launch_bounds__(256, 3) void attn_kernel(
    const _Float16* __restrict__ Qh, const _Float16* __restrict__ Kh,
    const _Float16* __restrict__ VT, _Float16* __restrict__ attn_out) {
  constexpr int PV_LD = 72;    // 64 + 8 pad (chunk-local key columns)
  __shared__ __align__(16) _Float16 Ksb[2][128 * 64];     // swizzled K tiles
  __shared__ __align__(16) _Float16 Ps[4 * 32 * PV_LD];   // per-wave P chunks

  const int n    = blockIdx.x;          // 0..511
  const int slot = n >> 3;
  const int bh   = (n & 7) * 4 + (slot >> 4);   // 16 q-blocks of a bh share XCD
  const int q0   = (slot & 15) * 128;
  const size_t base = (size_t)bh * Sn * HDn;    // same stride for Qh/Kh/VT

  const int tid  = threadIdx.x;
  const int lane = tid & 63;
  const int w    = tid >> 6;
  const int qd   = lane >> 4;
  const int lm   = lane & 15;

  // Q fragments direct from global (B-operand of S^T = K Q^T), once.
  const _Float16* qptr = Qh + base + (size_t)(q0 + w * 32 + lm) * HDn + qd * 8;
  half8 qa[2][2];
#pragma unroll
  for (int nj = 0; nj < 2; nj++)
#pragma unroll
    for (int ks = 0; ks < 2; ks++)
      qa[nj][ks] = *(const half8*)(qptr + nj * 16 * HDn + ks * 32);

  // ones A-fragment for the l row-sum MFMA: A[0][k]=1, other rows 0
  half8 vones;
#pragma unroll
  for (int j = 0; j < 8; j++) vones[j] = (lm == 0) ? (_Float16)1.0f : (_Float16)0.0f;

  f32x4 oacc[2][4];      // O^T: rows=hd, cols=q
#pragma unroll
  for (int i = 0; i < 2; i++)
#pragma unroll
    for (int j = 0; j < 4; j++) oacc[i][j] = {0.f, 0.f, 0.f, 0.f};
  f32x4 oaccl[2] = {{0.f, 0.f, 0.f, 0.f}, {0.f, 0.f, 0.f, 0.f}};  // l in row 0

  _Float16* Psw = Ps + w * (32 * PV_LD);
  const f32x4 sinit = {-10.f, -10.f, -10.f, -10.f};   // fixed softmax shift

  // swizzled K stage: LDS slot s (16B) holds global granule u^(row&7) of row s>>3
  const int st_r = tid >> 3;
  const int st_u = (tid & 7) ^ (st_r & 7);
  const _Float16* kbase = Kh + base;

#define STAGE_K(KT, DST)                                                     \
  {                                                                          \
    const _Float16* src_ = kbase + (size_t)(KT) * 128 * HDn;                 \
    _Float16* dst_ = (DST);                                                  \
    _Pragma("unroll")                                                        \
    for (int p = 0; p < 4; p++)                                              \
      cp16(src_ + (size_t)(st_r + p * 32) * HDn + st_u * 8,                  \
           dst_ + (tid + p * 256) * 8);                                      \
  }

  STAGE_K(0, Ksb[0])
  __syncthreads();

  int cur = 0;
  for (int kt = 0; kt < Sn / 128; kt++) {
    const int kb = kt * 128;
    if (kt + 1 < Sn / 128) STAGE_K(kt + 1, Ksb[cur ^ 1])

#pragma unroll
    for (int c = 0; c < 2; c++) {        // 64-key chunk: blocks ni = 4c..4c+3
      // S^T = K Q^T for this chunk (reads K rows 64c..64c+63 only)
      f32x4 sacc[4][2];
#pragma unroll
      for (int n4 = 0; n4 < 4; n4++)
#pragma unroll
        for (int nj = 0; nj < 2; nj++) sacc[n4][nj] = sinit;
#pragma unroll
      for (int n4 = 0; n4 < 4; n4++) {
        int ni = 4 * c + n4;
#pragma unroll
        for (int ks = 0; ks < 2; ks++) {
          int up = (4 * ks + qd) ^ (lm & 7);   // row&7 == lm&7
          half8 ka = *(const half8*)(Ksb[cur] + (ni * 16 + lm) * HDn + up * 8);
#pragma unroll
          for (int nj = 0; nj < 2; nj++)
            sacc[n4][nj] = __builtin_amdgcn_mfma_f32_16x16x32_f16(ka, qa[nj][ks], sacc[n4][nj], 0, 0, 0);
        }
      }

      // V fragments for this chunk, direct global (issued early, used in PV)
      half8 vb[4][2];   // [oi][k2]
#pragma unroll
      for (int oi = 0; oi < 4; oi++)
#pragma unroll
        for (int k2 = 0; k2 < 2; k2++)
          vb[oi][k2] = *(const half8*)(VT + base + (size_t)(oi * 16 + lm) * Sn
                                       + kb + c * 64 + k2 * 32 + qd * 8);

      // p = exp2(s), pack, store to wave-private LDS (chunk-local columns)
#pragma unroll
      for (int nj = 0; nj < 2; nj++)
#pragma unroll
        for (int n4 = 0; n4 < 4; n4++) {
          float p0 = __builtin_amdgcn_exp2f(sacc[n4][nj][0]);
          float p1 = __builtin_amdgcn_exp2f(sacc[n4][nj][1]);
          float p2 = __builtin_amdgcn_exp2f(sacc[n4][nj][2]);
          float p3 = __builtin_amdgcn_exp2f(sacc[n4][nj][3]);
          auto lo = __builtin_amdgcn_cvt_pkrtz(p0, p1);
          auto hi = __builtin_amdgcn_cvt_pkrtz(p2, p3);
          half4 h4;
          h4[0] = (_Float16)lo[0]; h4[1] = (_Float16)lo[1];
          h4[2] = (_Float16)hi[0]; h4[3] = (_Float16)hi[1];
          *(half4*)(Psw + (nj * 16 + lm) * PV_LD + n4 * 16 + qd * 4) = h4;
        }

      // O^T += V^T P^T ; l += ones . P
#pragma unroll
      for (int k2 = 0; k2 < 2; k2++) {
        half8 pa[2];
#pragma unroll
        for (int mi = 0; mi < 2; mi++)
          pa[mi] = *(const half8*)(Psw + (mi * 16 + lm) * PV_LD + k2 * 32 + qd * 8);
#pragma unroll
        for (int oi = 0; oi < 4; oi++)
#pragma unroll
          for (int mi = 0; mi < 2; mi++)
            oacc[mi][oi] = __builtin_amdgcn_mfma_f32_16x16x32_f16(vb[oi][k2], pa[mi], oacc[mi][oi], 0, 0, 0);
#pragma unroll
        for (int mi = 0; mi < 2; mi++)
          oaccl[mi] = __builtin_amdgcn_mfma_f32_16x16x32_f16(vones, pa[mi], oaccl[mi], 0, 0, 0);
      }
    }

    __syncthreads();   // single barrier/kt: syncs waves + drains prefetch DMA
    cur ^= 1;
  }
#undef STAGE_K

  // finalize: O^T cols = q (lm), l[q] lives in lane (qd=0, lm=q) reg 0.
  const int b_ = bh >> 4, h_ = bh & 15;
#pragma unroll
  for (int mi = 0; mi < 2; mi++) {
    float lr = __shfl(oaccl[mi][0], lm, 64);   // bpermute from qd=0 lanes
    float inv = 1.0f / lr;
    int qrow = q0 + w * 32 + mi * 16 + lm;
    size_t rowbase = ((size_t)(b_ * Sn + qrow)) * Dn + h_ * 64;
#pragma unroll
    for (int oi = 0; oi < 4; oi++) {
      half4 h4;
#pragma unroll
      for (int r = 0; r < 4; r++) h4[r] = (_Float16)(oacc[mi][oi][r] * inv);
      *(half4*)(attn_out + rowbase + oi * 16 + qd * 4) = h4;
    }
  }
}

// ---------------------------------------------------------------------------
// Kernel 3: output projection, transposed MFMA -> float4 stores.
// ---------------------------------------------------------------------------
__global__ __launch_bounds__(256) void outproj_kernel(
    const _Float16* __restrict__ Aattn, const _Float16* __restrict__ WoT,
    const float* __restrict__ bo, float* __restrict__ out) {
  __shared__ __align__(16) _Float16 As[128 * 32];
  __shared__ __align__(16) _Float16 Bs[128 * 32];

  const int tid  = threadIdx.x;
  const int lane = tid & 63;
  const int w    = tid >> 6;
  const int wm   = (w >> 1) * 64;
  const int wn   = (w & 1) * 64;
  const int m0   = blockIdx.y * 128;
  const int n0   = blockIdx.x * 128;
  const int qd   = lane >> 4;
  const int lm   = lane & 15;

  f32x4 acc[4][4];
#pragma unroll
  for (int i = 0; i < 4; i++)
#pragma unroll
    for (int j = 0; j < 4; j++) acc[i][j] = {0.f, 0.f, 0.f, 0.f};

  for (int k0 = 0; k0 < Dn; k0 += 32) {
#pragma unroll
    for (int p = 0; p < 2; p++) {
      int s = tid + p * 256;
      int row = s >> 2, c = s & 3;
      cp16(Aattn + (size_t)(m0 + row) * Dn + k0 + c * 8, As + s * 8);
    }
#pragma unroll
    for (int p = 0; p < 2; p++) {
      int s = tid + p * 256;
      int row = s >> 2, c = s & 3;
      cp16(WoT + (size_t)(n0 + row) * Dn + k0 + c * 8, Bs + s * 8);
    }
    __syncthreads();
    half8 a[4], bb[4];
#pragma unroll
    for (int mi = 0; mi < 4; mi++)
      a[mi] = *(const half8*)(As + (wm + mi * 16 + lm) * 32 + qd * 8);
#pragma unroll
    for (int ni = 0; ni < 4; ni++)
      bb[ni] = *(const half8*)(Bs + (wn + ni * 16 + lm) * 32 + qd * 8);
#pragma unroll
    for (int mi = 0; mi < 4; mi++)
#pragma unroll
      for (int ni = 0; ni < 4; ni++)
        acc[mi][ni] = __builtin_amdgcn_mfma_f32_16x16x32_f16(bb[ni], a[mi], acc[mi][ni], 0, 0, 0);
    __syncthreads();
  }
#pragma unroll
  for (int mi = 0; mi < 4; mi++) {
    int m = m0 + wm + mi * 16 + lm;              // token (D col)
#pragma unroll
    for (int ni = 0; ni < 4; ni++) {
      int nb = n0 + wn + ni * 16 + qd * 4;       // feature base (D rows)
      float4 b4 = *(const float4*)(bo + nb);
      float4 o4;
      o4.x = acc[mi][ni][0] + b4.x;
      o4.y = acc[mi][ni][1] + b4.y;
      o4.z = acc[mi][ni][2] + b4.z;
      o4.w = acc[mi][ni][3] + b4.w;
      *(float4*)(out + (size_t)m * Dn + nb) = o4;
    }
  }
}

extern "C" void kernel_launch(void* const* d_in, const int* in_sizes, int n_in,
                              void* d_out, int out_size, void* d_ws, size_t ws_size,
                              hipStream_t stream) {
  const float* query = (const float*)d_in[0];
  const float* key_  = (const float*)d_in[1];
  const float* value = (const float*)d_in[2];
  const float* Wq = (const float*)d_in[3];
  const float* bq = (const float*)d_in[4];
  const float* Wk = (const float*)d_in[5];
  const float* bk = (const float*)d_in[6];
  const float* Wv = (const float*)d_in[7];
  const float* bv = (const float*)d_in[8];
  const float* Wo = (const float*)d_in[9];
  const float* bo = (const float*)d_in[10];

  _Float16* Xh = (_Float16*)d_ws;                  // [3][4096][1024] f16 = 25.2 MB
  _Float16* WT = Xh + (size_t)3 * Mn * Dn;         // [4][1024][1024] f16 = 8.4 MB
  _Float16* Qh = WT + (size_t)4 * Dn * Dn;         // [b][h][s][hd]  8.4 MB
  _Float16* Kh = Qh + (size_t)Mn * Dn;             // [b][h][s][hd]  8.4 MB
  _Float16* VT = Kh + (size_t)Mn * Dn;             // [b][h][hd][s]  8.4 MB
  _Float16* attnb = Xh;                            // alias: Xh dead after proj
  float* out = (float*)d_out;

  dim3 blk(256);
  convert_x<<<dim3((Mn * Dn) / (4 * 256), 3), blk, 0, stream>>>(query, key_, value, Xh);
  transpose_w<<<dim3(16, 16, 4), blk, 0, stream>>>(Wq, Wk, Wv, Wo, WT);
  proj_kernel<<<dim3(Dn / 128, Mn / 128, 3), blk, 0, stream>>>(
      Xh, WT, bq, bk, bv, Qh, Kh, VT);
  attn_kernel<<<dim3(512), blk, 0, stream>>>(Qh, Kh, VT, attnb);
  outproj_kernel<<<dim3(Dn / 128, Mn / 128), blk, 0, stream>>>(
      attnb, WT + (size_t)3 * Dn * Dn, bo, out);
}